// Round 16
// baseline (205.420 us; speedup 1.0000x reference)
//
#include <hip/hip_runtime.h>
#include <hip/hip_bf16.h>

typedef __attribute__((ext_vector_type(4)))  float f32x4;
typedef __attribute__((ext_vector_type(16))) float f32x16;
typedef __attribute__((ext_vector_type(8)))  short bf16x8;
typedef __attribute__((ext_vector_type(4)))  short bf16x4;

#define DEVI static __device__ __forceinline__
#define WAITV(N) asm volatile("s_waitcnt vmcnt(" #N ")" ::: "memory")
#define BAR() __builtin_amdgcn_s_barrier()
#define SCHEDB() __builtin_amdgcn_sched_barrier(0)

constexpr int Bn = 4, Sn = 2048, Hn = 1024, NHn = 16, HDn = 64;
constexpr int Kn = 1024, Nn = 1024;
constexpr float QSCALE = 0.18033688011112042f;    // log2(e)/8

DEVI unsigned short f2bf(float x) {               // RNE f32->bf16 (scalar, epilogue only)
    union { float f; unsigned u; } v; v.f = x;
    unsigned r = v.u + 0x7fffu + ((v.u >> 16) & 1u);
    return (unsigned short)(r >> 16);
}

DEVI f32x4 mfma16(bf16x8 a, bf16x8 b, f32x4 c) {
    return __builtin_amdgcn_mfma_f32_16x16x32_bf16(a, b, c, 0, 0, 0);
}
DEVI f32x16 mfma32(bf16x8 a, bf16x8 b, f32x16 c) {
    return __builtin_amdgcn_mfma_f32_32x32x16_bf16(a, b, c, 0, 0, 0);
}
DEVI unsigned cvt_pk_bf16(float lo, float hi) {   // one v_cvt_pk_bf16_f32 (RNE)
    unsigned r;
    asm("v_cvt_pk_bf16_f32 %0, %1, %2" : "=v"(r) : "v"(lo), "v"(hi));
    return r;
}
// v_permlane32_swap_b32: a' = {a_lo, b_lo}, b' = {a_hi, b_hi}.
// ONLY use with distinct-valued operands.
DEVI void pl32swap(unsigned &a, unsigned &b) {
    asm("v_permlane32_swap_b32 %0, %1" : "+v"(a), "+v"(b));
}
DEVI float exp2_raw(float x) { return __builtin_amdgcn_exp2f(x); }

typedef const __attribute__((address_space(1))) void* gas1_t;
typedef __attribute__((address_space(3))) void* gas3_t;

// ---------------- weight fp32 -> bf16 ----------------
__global__ void convert_w_kernel(const float* __restrict__ w0, const float* __restrict__ w1,
                                 const float* __restrict__ w2, const float* __restrict__ w3,
                                 unsigned short* __restrict__ out)
{
    int mat = blockIdx.x >> 10;
    int i4  = ((blockIdx.x & 1023) << 8) + threadIdx.x;
    const float* w = mat == 0 ? w0 : mat == 1 ? w1 : mat == 2 ? w2 : w3;
    f32x4 v = *reinterpret_cast<const f32x4*>(w + (size_t)i4 * 4);
    union { unsigned u[2]; bf16x4 s; } pk;
    pk.u[0] = cvt_pk_bf16(v[0], v[1]);
    pk.u[1] = cvt_pk_bf16(v[2], v[3]);
    *reinterpret_cast<bf16x4*>(out + (((size_t)mat) << 20) + (size_t)i4 * 4) = pk.s;
}

// ---------------- out-projection GEMM: BK=64, dbuf prefetch, 1 barrier/step ----------
__global__ __launch_bounds__(256, 2)
void out_proj_kernel(const unsigned short* __restrict__ Aw, const unsigned short* __restrict__ Bw,
                     const float* __restrict__ bias, float* __restrict__ Out)
{
    __shared__ __align__(16) unsigned short As[2][128 * 64];   // 2 x 16KB
    __shared__ __align__(16) unsigned short Bs[2][128 * 64];   // 2 x 16KB

    const int tid = threadIdx.x;
    const int wid = tid >> 6, lane = tid & 63;
    const int lhi = lane >> 4, llo = lane & 15;
    const int bid = blockIdx.x;
    const int sid = (bid & 7) * 64 + (bid >> 3);     // T1 XCD swizzle, nwg=512
    const int bx = sid & 7, by = sid >> 3;
    const int brow = by * 128, bcol = bx * 128;
    const int wr = wid >> 1, wc = wid & 1;

    // bf16 tile = 128x64 = 1024 16B-chunks; chunk c = r*256+tid: row=c>>3, col8=(c&7)*8
    const int trow = tid >> 3, tcol = (tid & 7) * 8;
    const int aBase = (brow + trow) * Kn + tcol;     // + r*32*Kn + kt*64
    const int bBase = (bcol + trow) * Kn + tcol;

    f32x4 acc[4][4] = {};

    auto stage = [&](int buf, int kt) {
        #pragma unroll
        for (int r = 0; r < 4; ++r)
            __builtin_amdgcn_global_load_lds(
                (gas1_t)(Bw + (size_t)(bBase + r * 32 * Kn + kt * 64)),
                (gas3_t)(Bs[buf] + (size_t)(r * 256 + wid * 64) * 8), 16, 0, 0);
        #pragma unroll
        for (int r = 0; r < 4; ++r)
            __builtin_amdgcn_global_load_lds(
                (gas1_t)(Aw + (size_t)(aBase + r * 32 * Kn + kt * 64)),
                (gas3_t)(As[buf] + (size_t)(r * 256 + wid * 64) * 8), 16, 0, 0);
    };
    auto compute = [&](int buf) {
        #pragma unroll
        for (int kk = 0; kk < 2; ++kk) {
            bf16x8 a[4], b[4];
            #pragma unroll
            for (int m = 0; m < 4; ++m)
                a[m] = *reinterpret_cast<const bf16x8*>(As[buf] + (wr * 64 + m * 16 + llo) * 64 + kk * 32 + lhi * 8);
            #pragma unroll
            for (int n = 0; n < 4; ++n)
                b[n] = *reinterpret_cast<const bf16x8*>(Bs[buf] + (wc * 64 + n * 16 + llo) * 64 + kk * 32 + lhi * 8);
            #pragma unroll
            for (int m = 0; m < 4; ++m)
                #pragma unroll
                for (int n = 0; n < 4; ++n)
                    acc[m][n] = mfma16(a[m], b[n], acc[m][n]);
        }
    };

    constexpr int NKT = Kn / 64;                     // 16
    stage(0, 0);
    __syncthreads();
    for (int kt = 0; kt < NKT; ++kt) {
        if (kt + 1 < NKT) stage((kt + 1) & 1, kt + 1);   // latency hides under compute
        compute(kt & 1);
        __syncthreads();                                  // drains prefetch + buffer reuse
    }

    #pragma unroll
    for (int m = 0; m < 4; ++m)
        #pragma unroll
        for (int n = 0; n < 4; ++n) {
            const int col  = bcol + wc * 64 + n * 16 + llo;
            const int row0 = brow + wr * 64 + m * 16 + lhi * 4;
            const float bv = bias[col];
            #pragma unroll
            for (int r = 0; r < 4; ++r)
                Out[(size_t)(row0 + r) * Nn + col] = acc[m][n][r] + bv;
        }
}

// ---------------- QKV projection: BK=64 dbuf async-split fp32-A staging ----------
// 32 MFMA per barrier interval (was 16), 16 K-steps (was 32): halves both the
// exposed A-latency windows and the barrier drains. Same proven sync shape.
__global__ __launch_bounds__(256, 2)
void qkv_proj_kernel(const float* __restrict__ xq, const float* __restrict__ xk,
                     const float* __restrict__ xv, const unsigned short* __restrict__ Wb,
                     const float* __restrict__ bq, const float* __restrict__ bk,
                     const float* __restrict__ bv,
                     unsigned short* __restrict__ Qw, unsigned short* __restrict__ Kw,
                     unsigned short* __restrict__ Vw)
{
    __shared__ __align__(16) unsigned short As[2][128 * 64];   // 2 x 16KB bf16
    __shared__ __align__(16) unsigned short Bs[2][128 * 64];   // 2 x 16KB bf16

    const int z = blockIdx.z;
    const float* A           = z == 0 ? xq : z == 1 ? xk : xv;
    const unsigned short* W  = Wb + (((size_t)z) << 20);
    const float* bias        = z == 0 ? bq : z == 1 ? bk : bv;
    unsigned short* Out      = z == 0 ? Qw : z == 1 ? Kw : Vw;
    const float scale        = z == 0 ? QSCALE : 1.0f;

    const int tid = threadIdx.x;
    const int wid = tid >> 6, lane = tid & 63;
    const int lhi = lane >> 4, llo = lane & 15;
    const int bid = blockIdx.x;
    const int sid = (bid & 7) * 64 + (bid >> 3);     // T1 XCD swizzle
    const int bx = sid & 7, by = sid >> 3;
    const int brow = by * 128, bcol = bx * 128;
    const int wr = wid >> 1, wc = wid & 1;

    // A fp32 tile 128x64 = 2048 16B-chunks; chunk c = r*256+tid: row=c>>4, col4=(c&15)*4
    const int arow = tid >> 4, acol = (tid & 15) * 4;
    const int aBase = (brow + arow) * Kn + acol;     // + r*16*Kn + kt*64 (float idx)
    const int aLds  = arow * 64 + acol;              // + r*16*64 = r*1024 (elem idx)
    // B bf16 tile 128x64 = 1024 16B-chunks; chunk c = r*256+tid: row=c>>3, col8=(c&7)*8
    const int brw = tid >> 3, bcl = (tid & 7) * 8;
    const int bBase = (bcol + brw) * Kn + bcl;       // + r*32*Kn + kt*64 (ushort idx)

    f32x4 acc[4][4] = {};
    f32x4 ar[8];                                     // A prefetch regs (one tile)

    auto issueA = [&](int kt) {
        #pragma unroll
        for (int r = 0; r < 8; ++r)
            ar[r] = *reinterpret_cast<const f32x4*>(A + (size_t)(aBase + r * 16 * Kn + kt * 64));
    };
    auto stageB = [&](int buf, int kt) {
        #pragma unroll
        for (int r = 0; r < 4; ++r)
            __builtin_amdgcn_global_load_lds(
                (gas1_t)(W + (size_t)(bBase + r * 32 * Kn + kt * 64)),
                (gas3_t)(Bs[buf] + (size_t)(r * 256 + wid * 64) * 8), 16, 0, 0);
    };
    auto writeA = [&](int buf) {
        #pragma unroll
        for (int r = 0; r < 8; ++r) {
            union { unsigned u[2]; bf16x4 s; } pk;
            pk.u[0] = cvt_pk_bf16(ar[r][0], ar[r][1]);
            pk.u[1] = cvt_pk_bf16(ar[r][2], ar[r][3]);
            *reinterpret_cast<bf16x4*>(As[buf] + aLds + r * 1024) = pk.s;
        }
    };
    auto compute = [&](int buf) {
        #pragma unroll
        for (int kk = 0; kk < 2; ++kk) {
            bf16x8 a[4], b[4];
            #pragma unroll
            for (int m = 0; m < 4; ++m)
                a[m] = *reinterpret_cast<const bf16x8*>(As[buf] + (wr * 64 + m * 16 + llo) * 64 + kk * 32 + lhi * 8);
            #pragma unroll
            for (int n = 0; n < 4; ++n)
                b[n] = *reinterpret_cast<const bf16x8*>(Bs[buf] + (wc * 64 + n * 16 + llo) * 64 + kk * 32 + lhi * 8);
            #pragma unroll
            for (int m = 0; m < 4; ++m)
                #pragma unroll
                for (int n = 0; n < 4; ++n)
                    acc[m][n] = mfma16(a[m], b[n], acc[m][n]);
        }
    };

    constexpr int NKT = Kn / 64;                     // 16, even
    issueA(0);
    stageB(0, 0);
    writeA(0);                                       // compiler waits vmcnt for ar only
    __syncthreads();                                 // drains B(0) gload_lds

    for (int kt = 0; kt < NKT; kt += 2) {
        issueA(kt + 1);                              // prefetch hides under compute
        stageB(1, kt + 1);
        compute(0);
        writeA(1);
        __syncthreads();
        if (kt + 2 < NKT) { issueA(kt + 2); stageB(0, kt + 2); }
        compute(1);
        if (kt + 2 < NKT) writeA(0);
        __syncthreads();
    }

    // --- epilogue: C/D layout col=lane&15, row=(lane>>4)*4+reg
    #pragma unroll
    for (int m = 0; m < 4; ++m) {
        #pragma unroll
        for (int n = 0; n < 4; ++n) {
            const int col  = bcol + wc * 64 + n * 16 + llo;
            const int row0 = brow + wr * 64 + m * 16 + lhi * 4;
            const float bv = bias[col];
            const int hh = col >> 6, d = col & 63;
            if (z != 2) {                            // Q/K layout [b,h,s,d] (Q pre-scaled)
                unsigned short* O = (unsigned short*)Out;
                #pragma unroll
                for (int r = 0; r < 4; ++r) {
                    int rowm = row0 + r;
                    int bb = rowm >> 11, ss = rowm & 2047;
                    O[((((size_t)bb * NHn + hh) * Sn + ss) << 6) + d] =
                        f2bf((acc[m][n][r] + bv) * scale);
                }
            } else {                                 // V transposed [b,h,d,s]
                unsigned short* O = (unsigned short*)Out;
                const int bb = row0 >> 11, ss = row0 & 2047;
                union { unsigned u[2]; bf16x4 s; } pk;
                pk.u[0] = cvt_pk_bf16(acc[m][n][0] + bv, acc[m][n][1] + bv);
                pk.u[1] = cvt_pk_bf16(acc[m][n][2] + bv, acc[m][n][3] + bv);
                *reinterpret_cast<bf16x4*>(O + (((size_t)bb * NHn + hh) * HDn + d) * Sn + ss) = pk.s;
            }
        }
    }
}

// ---------------- flash attention: triple-buffered K/V, counted vmcnt ----------------
__global__ __launch_bounds__(256, 2)
void attn_kernel(const unsigned short* __restrict__ Q, const unsigned short* __restrict__ K,
                 const unsigned short* __restrict__ Vt, unsigned short* __restrict__ On)
{
    __shared__ __align__(16) unsigned short LDST[3 * 8192];   // 3 bufs x (K 8KB + V 8KB)

    const int tid = threadIdx.x;
    const int wid = tid >> 6, lane = tid & 63;
    const int l31 = lane & 31, h = lane >> 5;
    const int bid = blockIdx.x;
    const int sid = (bid & 7) * 64 + (bid >> 3);
    const int bh = sid >> 3;
    const int qt = sid & 7;
    const int q0 = qt * 256 + wid * 64;

    const unsigned short* Qb = Q + (size_t)bh * Sn * HDn;
    const unsigned short* Kb = K + (size_t)bh * Sn * HDn;
    const unsigned short* Vb = Vt + (size_t)bh * HDn * Sn;

    int koff[2], voff[2];
    #pragma unroll
    for (int r = 0; r < 2; ++r) {
        int lin = (r * 256 + tid) * 16;
        int row = lin >> 7, colb = lin & 127;
        int scolb = colb ^ ((row & 7) << 4);
        koff[r] = row * HDn + (scolb >> 1);
        voff[r] = row * Sn + (scolb >> 1);
    }

    auto stage = [&](int bufEl, int key0) {          // bufEl in {0, 8192, 16384} elements
        #pragma unroll
        for (int r = 0; r < 2; ++r)
            __builtin_amdgcn_global_load_lds((gas1_t)(Kb + koff[r] + key0 * HDn),
                (gas3_t)(LDST + bufEl + r * 2048 + wid * 512), 16, 0, 0);
        #pragma unroll
        for (int r = 0; r < 2; ++r)
            __builtin_amdgcn_global_load_lds((gas1_t)(Vb + voff[r] + key0),
                (gas3_t)(LDST + bufEl + 4096 + r * 2048 + wid * 512), 16, 0, 0);
    };
    auto rdT = [&](int byteoff) -> bf16x8 {
        return *reinterpret_cast<const bf16x8*>((const char*)LDST + byteoff);
    };
    const int lrow = l31 * 128;
    const int lswz = (l31 & 7) << 4;

    bf16x8 qfA[4], qfB[4];
    #pragma unroll
    for (int sd = 0; sd < 4; ++sd) {
        qfA[sd] = *reinterpret_cast<const bf16x8*>(Qb + (size_t)(q0 + l31) * HDn + sd * 16 + h * 8);
        qfB[sd] = *reinterpret_cast<const bf16x8*>(Qb + (size_t)(q0 + 32 + l31) * HDn + sd * 16 + h * 8);
    }

    f32x16 oA0 = {}, oA1 = {}, oB0 = {}, oB1 = {};
    float lA = 0.f, lB = 0.f;

    auto body = [&](int base) {
        bf16x8 ka0[4], ka1[4];
        #pragma unroll
        for (int sd = 0; sd < 4; ++sd) {
            int la = lrow + ((sd * 32 + h * 16) ^ lswz);
            ka0[sd] = rdT(base + la);
            ka1[sd] = rdT(base + 4096 + la);
        }
        f32x16 sA0 = {}, sA1 = {}, sB0 = {}, sB1 = {};
        __builtin_amdgcn_s_setprio(1);
        #pragma unroll
        for (int sd = 0; sd < 4; ++sd) sA0 = mfma32(ka0[sd], qfA[sd], sA0);
        #pragma unroll
        for (int sd = 0; sd < 4; ++sd) sA1 = mfma32(ka1[sd], qfA[sd], sA1);
        #pragma unroll
        for (int sd = 0; sd < 4; ++sd) sB0 = mfma32(ka0[sd], qfB[sd], sB0);
        #pragma unroll
        for (int sd = 0; sd < 4; ++sd) sB1 = mfma32(ka1[sd], qfB[sd], sB1);
        __builtin_amdgcn_s_setprio(0);

        bf16x8 va0[4], va1[4];
        #pragma unroll
        for (int S = 0; S < 4; ++S) {
            int la = lrow + ((S * 32 + h * 16) ^ lswz);
            va0[S] = rdT(base + 8192 + la);
            va1[S] = rdT(base + 8192 + 4096 + la);
        }

        #pragma unroll
        for (int r = 0; r < 16; ++r) {
            sA0[r] = exp2_raw(sA0[r]); sA1[r] = exp2_raw(sA1[r]);
            sB0[r] = exp2_raw(sB0[r]); sB1[r] = exp2_raw(sB1[r]);
        }

        {
            float sa[16], sb[16];
            #pragma unroll
            for (int r = 0; r < 16; ++r) { sa[r] = sA0[r] + sA1[r]; sb[r] = sB0[r] + sB1[r]; }
            #pragma unroll
            for (int st = 8; st > 0; st >>= 1)
                #pragma unroll
                for (int r = 0; r < 8; ++r)
                    if (r < st) { sa[r] += sa[r + st]; sb[r] += sb[r + st]; }
            lA += sa[0];
            lB += sb[0];
        }

        unsigned WpA[2][4][2], WpB[2][4][2];
        #pragma unroll
        for (int R = 0; R < 4; ++R) {
            WpA[0][R][0] = cvt_pk_bf16(sA0[4 * R],     sA0[4 * R + 1]);
            WpA[0][R][1] = cvt_pk_bf16(sA0[4 * R + 2], sA0[4 * R + 3]);
            WpA[1][R][0] = cvt_pk_bf16(sA1[4 * R],     sA1[4 * R + 1]);
            WpA[1][R][1] = cvt_pk_bf16(sA1[4 * R + 2], sA1[4 * R + 3]);
            WpB[0][R][0] = cvt_pk_bf16(sB0[4 * R],     sB0[4 * R + 1]);
            WpB[0][R][1] = cvt_pk_bf16(sB0[4 * R + 2], sB0[4 * R + 3]);
            WpB[1][R][0] = cvt_pk_bf16(sB1[4 * R],     sB1[4 * R + 1]);
            WpB[1][R][1] = cvt_pk_bf16(sB1[4 * R + 2], sB1[4 * R + 3]);
        }

        #pragma unroll
        for (int kc = 0; kc < 2; ++kc) {
            #pragma unroll
            for (int sp = 0; sp < 2; ++sp) {
                const int S = kc * 2 + sp;
                unsigned a0 = WpA[kc][2 * sp][0], a2 = WpA[kc][2 * sp + 1][0];
                unsigned a1 = WpA[kc][2 * sp][1], a3 = WpA[kc][2 * sp + 1][1];
                pl32swap(a0, a2);
                pl32swap(a1, a3);
                union { unsigned u[4]; bf16x8 v; } pbA;
                pbA.u[0] = a0; pbA.u[1] = a1; pbA.u[2] = a2; pbA.u[3] = a3;
                unsigned b0 = WpB[kc][2 * sp][0], b2 = WpB[kc][2 * sp + 1][0];
                unsigned b1 = WpB[kc][2 * sp][1], b3 = WpB[kc][2 * sp + 1][1];
                pl32swap(b0, b2);
                pl32swap(b1, b3);
                union { unsigned u[4]; bf16x8 v; } pbB;
                pbB.u[0] = b0; pbB.u[1] = b1; pbB.u[2] = b2; pbB.u[3] = b3;
                __builtin_amdgcn_s_setprio(1);
                oA0 = mfma32(va0[S], pbA.v, oA0);
                oA1 = mfma32(va1[S], pbA.v, oA1);
                oB0 = mfma32(va0[S], pbB.v, oB0);
                oB1 = mfma32(va1[S], pbB.v, oB1);
                __builtin_amdgcn_s_setprio(0);
            }
        }
    };

    constexpr int NT = Sn / 64;                      // 32
    stage(0, 0);
    int ec = 0, en = 8192, e2 = 16384;
    for (int n = 0; n < NT; ++n) {
        if (n + 1 < NT) {
            stage(en, (n + 1) * 64);
            WAITV(4);
        } else {
            WAITV(0);
        }
        BAR(); SCHEDB();
        body(ec * 2);
        int t = ec; ec = en; en = e2; e2 = t;
    }

    lA += __shfl_xor(lA, 32, 64);
    lB += __shfl_xor(lB, 32, 64);
    const float invA = 1.f / lA, invB = 1.f / lB;
    const int b = bh >> 4, hh = bh & 15;
    unsigned short* OrowA = On + ((size_t)b * Sn + (q0 + l31))      * Hn + hh * 64;
    unsigned short* OrowB = On + ((size_t)b * Sn + (q0 + 32 + l31)) * Hn + hh * 64;
    #pragma unroll
    for (int g = 0; g < 4; ++g) {
        union { unsigned u[2]; bf16x4 s; } pA0, pA1, pB0, pB1;
        pA0.u[0] = cvt_pk_bf16(oA0[4 * g] * invA,     oA0[4 * g + 1] * invA);
        pA0.u[1] = cvt_pk_bf16(oA0[4 * g + 2] * invA, oA0[4 * g + 3] * invA);
        pA1.u[0] = cvt_pk_bf16(oA1[4 * g] * invA,     oA1[4 * g + 1] * invA);
        pA1.u[1] = cvt_pk_bf16(oA1[4 * g + 2] * invA, oA1[4 * g + 3] * invA);
        pB0.u[0] = cvt_pk_bf16(oB0[4 * g] * invB,     oB0[4 * g + 1] * invB);
        pB0.u[1] = cvt_pk_bf16(oB0[4 * g + 2] * invB, oB0[4 * g + 3] * invB);
        pB1.u[0] = cvt_pk_bf16(oB1[4 * g] * invB,     oB1[4 * g + 1] * invB);
        pB1.u[1] = cvt_pk_bf16(oB1[4 * g + 2] * invB, oB1[4 * g + 3] * invB);
        *reinterpret_cast<bf16x4*>(OrowA + g * 8 + 4 * h)      = pA0.s;
        *reinterpret_cast<bf16x4*>(OrowA + 32 + g * 8 + 4 * h) = pA1.s;
        *reinterpret_cast<bf16x4*>(OrowB + g * 8 + 4 * h)      = pB0.s;
        *reinterpret_cast<bf16x4*>(OrowB + 32 + g * 8 + 4 * h) = pB1.s;
    }
}

// ---------------- launch ----------------
extern "C" void kernel_launch(void* const* d_in, const int* in_sizes, int n_in,
                              void* d_out, int out_size, void* d_ws, size_t ws_size,
                              hipStream_t stream)
{
    (void)in_sizes; (void)n_in; (void)out_size;
    const float* q  = (const float*)d_in[0];
    const float* k  = (const float*)d_in[1];
    const float* v  = (const float*)d_in[2];
    const float* Wq = (const float*)d_in[3];
    const float* bq = (const float*)d_in[4];
    const float* Wk = (const float*)d_in[5];
    const float* bk = (const float*)d_in[6];
    const float* Wv = (const float*)d_in[7];
    const float* bv = (const float*)d_in[8];
    const float* Wo = (const float*)d_in[9];
    const float* bo = (const float*)d_in[10];
    float* out = (float*)d_out;

    if (ws_size < (size_t)72 * 1024 * 1024) return;

    unsigned short* Wb = (unsigned short*)d_ws;
    unsigned short* Qw = Wb + (size_t)4 * 1024 * 1024;
    unsigned short* Kw = Qw + (size_t)8 * 1024 * 1024;
    unsigned short* Vw = Kw + (size_t)8 * 1024 * 1024;
    unsigned short* Aw = Vw + (size_t)8 * 1024 * 1024;

    convert_w_kernel<<<4096, 256, 0, stream>>>(Wq, Wk, Wv, Wo, Wb);
    qkv_proj_kernel<<<dim3(512, 1, 3), 256, 0, stream>>>(q, k, v, Wb, bq, bk, bv, Qw, Kw, Vw);
    attn_kernel<<<512, 256, 0, stream>>>(Qw, Kw, Vw, Aw);
    out_proj_kernel<<<512, 256, 0, stream>>>(Aw, Wb + ((size_t)3 << 20), bo, out);
}

// Round 17
// 185.904 us; speedup vs baseline: 1.1050x; 1.1050x over previous
//
#include <hip/hip_runtime.h>
#include <hip/hip_bf16.h>

typedef __attribute__((ext_vector_type(4)))  float f32x4;
typedef __attribute__((ext_vector_type(16))) float f32x16;
typedef __attribute__((ext_vector_type(8)))  short bf16x8;
typedef __attribute__((ext_vector_type(4)))  short bf16x4;

#define DEVI static __device__ __forceinline__

constexpr int Bn = 4, Sn = 2048, Hn = 1024, NHn = 16, HDn = 64;
constexpr int Kn = 1024, Nn = 1024;
constexpr float QSCALE = 0.18033688011112042f;    // log2(e)/8

DEVI unsigned short f2bf(float x) {               // RNE f32->bf16 (scalar, epilogue only)
    union { float f; unsigned u; } v; v.f = x;
    unsigned r = v.u + 0x7fffu + ((v.u >> 16) & 1u);
    return (unsigned short)(r >> 16);
}

DEVI f32x4 mfma16(bf16x8 a, bf16x8 b, f32x4 c) {
    return __builtin_amdgcn_mfma_f32_16x16x32_bf16(a, b, c, 0, 0, 0);
}
DEVI f32x16 mfma32(bf16x8 a, bf16x8 b, f32x16 c) {
    return __builtin_amdgcn_mfma_f32_32x32x16_bf16(a, b, c, 0, 0, 0);
}
DEVI unsigned cvt_pk_bf16(float lo, float hi) {   // one v_cvt_pk_bf16_f32 (RNE)
    unsigned r;
    asm("v_cvt_pk_bf16_f32 %0, %1, %2" : "=v"(r) : "v"(lo), "v"(hi));
    return r;
}
// v_permlane32_swap_b32: a' = {a_lo, b_lo}, b' = {a_hi, b_hi}.
// ONLY use with distinct-valued operands.
DEVI void pl32swap(unsigned &a, unsigned &b) {
    asm("v_permlane32_swap_b32 %0, %1" : "+v"(a), "+v"(b));
}
DEVI float exp2_raw(float x) { return __builtin_amdgcn_exp2f(x); }

typedef const __attribute__((address_space(1))) void* gas1_t;
typedef __attribute__((address_space(3))) void* gas3_t;

// ---------------- weight fp32 -> bf16 ----------------
__global__ void convert_w_kernel(const float* __restrict__ w0, const float* __restrict__ w1,
                                 const float* __restrict__ w2, const float* __restrict__ w3,
                                 unsigned short* __restrict__ out)
{
    int mat = blockIdx.x >> 10;
    int i4  = ((blockIdx.x & 1023) << 8) + threadIdx.x;
    const float* w = mat == 0 ? w0 : mat == 1 ? w1 : mat == 2 ? w2 : w3;
    f32x4 v = *reinterpret_cast<const f32x4*>(w + (size_t)i4 * 4);
    union { unsigned u[2]; bf16x4 s; } pk;
    pk.u[0] = cvt_pk_bf16(v[0], v[1]);
    pk.u[1] = cvt_pk_bf16(v[2], v[3]);
    *reinterpret_cast<bf16x4*>(out + (((size_t)mat) << 20) + (size_t)i4 * 4) = pk.s;
}

// ---------------- out-projection GEMM (bf16 A via global_load_lds, BK=32) ----------------
__global__ __launch_bounds__(256, 2)
void out_proj_kernel(const unsigned short* __restrict__ Aw, const unsigned short* __restrict__ Bw,
                     const float* __restrict__ bias, float* __restrict__ Out)
{
    __shared__ __align__(16) unsigned short As[128 * 32];
    __shared__ __align__(16) unsigned short Bs[128 * 32];

    const int tid = threadIdx.x;
    const int wid = tid >> 6, lane = tid & 63;
    const int lhi = lane >> 4, llo = lane & 15;
    const int bid = blockIdx.x;
    const int sid = (bid & 7) * 64 + (bid >> 3);     // T1 XCD swizzle, nwg=512
    const int bx = sid & 7, by = sid >> 3;
    const int brow = by * 128, bcol = bx * 128;
    const int wr = wid >> 1, wc = wid & 1;

    f32x4 acc[4][4] = {};

    for (int kt = 0; kt < Kn / 32; ++kt) {
        __syncthreads();
        #pragma unroll
        for (int r = 0; r < 2; ++r) {
            int lin = r * 256 + tid;
            int row = lin >> 2, kc = (lin & 3) * 8;
            __builtin_amdgcn_global_load_lds(
                (gas1_t)(Bw + (size_t)(bcol + row) * Kn + kt * 32 + kc),
                (gas3_t)(Bs + (size_t)(r * 256 + wid * 64) * 8), 16, 0, 0);
        }
        #pragma unroll
        for (int r = 0; r < 2; ++r) {
            int lin = r * 256 + tid;
            int row = lin >> 2, kc = (lin & 3) * 8;
            __builtin_amdgcn_global_load_lds(
                (gas1_t)(Aw + (size_t)(brow + row) * Kn + kt * 32 + kc),
                (gas3_t)(As + (size_t)(r * 256 + wid * 64) * 8), 16, 0, 0);
        }
        __syncthreads();

        bf16x8 a[4], b[4];
        #pragma unroll
        for (int m = 0; m < 4; ++m)
            a[m] = *reinterpret_cast<const bf16x8*>(As + (wr * 64 + m * 16 + llo) * 32 + lhi * 8);
        #pragma unroll
        for (int n = 0; n < 4; ++n)
            b[n] = *reinterpret_cast<const bf16x8*>(Bs + (wc * 64 + n * 16 + llo) * 32 + lhi * 8);
        #pragma unroll
        for (int m = 0; m < 4; ++m)
            #pragma unroll
            for (int n = 0; n < 4; ++n)
                acc[m][n] = mfma16(a[m], b[n], acc[m][n]);
    }

    #pragma unroll
    for (int m = 0; m < 4; ++m)
        #pragma unroll
        for (int n = 0; n < 4; ++n) {
            const int col  = bcol + wc * 64 + n * 16 + llo;
            const int row0 = brow + wr * 64 + m * 16 + lhi * 4;
            const float bv = bias[col];
            #pragma unroll
            for (int r = 0; r < 4; ++r)
                Out[(size_t)(row0 + r) * Nn + col] = acc[m][n][r] + bv;
        }
}

// ---------------- QKV projection: double-buffered, async-split fp32-A staging (BK=32) ----
__global__ __launch_bounds__(256, 2)
void qkv_proj_kernel(const float* __restrict__ xq, const float* __restrict__ xk,
                     const float* __restrict__ xv, const unsigned short* __restrict__ Wb,
                     const float* __restrict__ bq, const float* __restrict__ bk,
                     const float* __restrict__ bv,
                     unsigned short* __restrict__ Qw, unsigned short* __restrict__ Kw,
                     unsigned short* __restrict__ Vw)
{
    __shared__ __align__(16) unsigned short As[2][128 * 32];
    __shared__ __align__(16) unsigned short Bs[2][128 * 32];

    const int z = blockIdx.z;
    const float* A           = z == 0 ? xq : z == 1 ? xk : xv;
    const unsigned short* W  = Wb + (((size_t)z) << 20);
    const float* bias        = z == 0 ? bq : z == 1 ? bk : bv;
    unsigned short* Out      = z == 0 ? Qw : z == 1 ? Kw : Vw;
    const float scale        = z == 0 ? QSCALE : 1.0f;

    const int tid = threadIdx.x;
    const int wid = tid >> 6, lane = tid & 63;
    const int lhi = lane >> 4, llo = lane & 15;
    const int bid = blockIdx.x;
    const int sid = (bid & 7) * 64 + (bid >> 3);     // T1 XCD swizzle
    const int bx = sid & 7, by = sid >> 3;
    const int brow = by * 128, bcol = bx * 128;
    const int wr = wid >> 1, wc = wid & 1;

    f32x4 acc[4][4] = {};

    auto issueA = [&](f32x4 (&ar)[4], int kt) {
        #pragma unroll
        for (int r = 0; r < 4; ++r) {
            int lin = r * 256 + tid;
            int row = lin >> 3, kc = (lin & 7) * 4;
            ar[r] = *reinterpret_cast<const f32x4*>(A + (size_t)(brow + row) * Kn + kt * 32 + kc);
        }
    };
    auto stageB = [&](int buf, int kt) {
        #pragma unroll
        for (int r = 0; r < 2; ++r) {
            int lin = r * 256 + tid;
            int row = lin >> 2, kc = (lin & 3) * 8;
            __builtin_amdgcn_global_load_lds(
                (gas1_t)(W + (size_t)(bcol + row) * Kn + kt * 32 + kc),
                (gas3_t)(Bs[buf] + (size_t)(r * 256 + wid * 64) * 8), 16, 0, 0);
        }
    };
    auto writeA = [&](int buf, f32x4 (&ar)[4]) {
        #pragma unroll
        for (int r = 0; r < 4; ++r) {
            int lin = r * 256 + tid;
            int row = lin >> 3, kc = (lin & 7) * 4;
            union { unsigned u[2]; bf16x4 s; } pk;
            pk.u[0] = cvt_pk_bf16(ar[r][0], ar[r][1]);
            pk.u[1] = cvt_pk_bf16(ar[r][2], ar[r][3]);
            *reinterpret_cast<bf16x4*>(As[buf] + row * 32 + kc) = pk.s;
        }
    };
    auto compute = [&](int buf) {
        bf16x8 a[4], b[4];
        #pragma unroll
        for (int m = 0; m < 4; ++m)
            a[m] = *reinterpret_cast<const bf16x8*>(As[buf] + (wr * 64 + m * 16 + llo) * 32 + lhi * 8);
        #pragma unroll
        for (int n = 0; n < 4; ++n)
            b[n] = *reinterpret_cast<const bf16x8*>(Bs[buf] + (wc * 64 + n * 16 + llo) * 32 + lhi * 8);
        #pragma unroll
        for (int m = 0; m < 4; ++m)
            #pragma unroll
            for (int n = 0; n < 4; ++n)
                acc[m][n] = mfma16(a[m], b[n], acc[m][n]);
    };

    constexpr int NKT = Kn / 32;                     // 32, even
    f32x4 ar0[4], ar1[4];

    issueA(ar0, 0);
    stageB(0, 0);
    writeA(0, ar0);                                  // compiler waits vmcnt for ar0 only
    __syncthreads();                                 // drains B(0) gload_lds

    for (int kt = 0; kt < NKT; kt += 2) {
        issueA(ar1, kt + 1);                         // prefetch next tile (latency hides
        stageB(1, kt + 1);                           //  under compute below)
        compute(0);
        writeA(1, ar1);
        __syncthreads();
        if (kt + 2 < NKT) { issueA(ar0, kt + 2); stageB(0, kt + 2); }
        compute(1);
        if (kt + 2 < NKT) writeA(0, ar0);
        __syncthreads();
    }

    // --- epilogue: C/D layout col=lane&15, row=(lane>>4)*4+reg
    #pragma unroll
    for (int m = 0; m < 4; ++m) {
        #pragma unroll
        for (int n = 0; n < 4; ++n) {
            const int col  = bcol + wc * 64 + n * 16 + llo;
            const int row0 = brow + wr * 64 + m * 16 + lhi * 4;
            const float bv = bias[col];
            const int hh = col >> 6, d = col & 63;
            if (z != 2) {                            // Q/K layout [b,h,s,d] (Q pre-scaled)
                unsigned short* O = (unsigned short*)Out;
                #pragma unroll
                for (int r = 0; r < 4; ++r) {
                    int rowm = row0 + r;
                    int bb = rowm >> 11, ss = rowm & 2047;
                    O[((((size_t)bb * NHn + hh) * Sn + ss) << 6) + d] =
                        f2bf((acc[m][n][r] + bv) * scale);
                }
            } else {                                 // V transposed [b,h,d,s]
                unsigned short* O = (unsigned short*)Out;
                const int bb = row0 >> 11, ss = row0 & 2047;
                union { unsigned u[2]; bf16x4 s; } pk;
                pk.u[0] = cvt_pk_bf16(acc[m][n][0] + bv, acc[m][n][1] + bv);
                pk.u[1] = cvt_pk_bf16(acc[m][n][2] + bv, acc[m][n][3] + bv);
                *reinterpret_cast<bf16x4*>(O + (((size_t)bb * NHn + hh) * HDn + d) * Sn + ss) = pk.s;
            }
        }
    }
}

// ---------------- flash attention (proven round-10 version) ----------------
__global__ __launch_bounds__(256, 2)
void attn_kernel(const unsigned short* __restrict__ Q, const unsigned short* __restrict__ K,
                 const unsigned short* __restrict__ Vt, unsigned short* __restrict__ On)
{
    __shared__ __align__(16) unsigned short LDST[2 * 2 * 4096];

    const int tid = threadIdx.x;
    const int wid = tid >> 6, lane = tid & 63;
    const int l31 = lane & 31, h = lane >> 5;
    const int bid = blockIdx.x;
    const int sid = (bid & 7) * 64 + (bid >> 3);
    const int bh = sid >> 3;
    const int qt = sid & 7;
    const int q0 = qt * 256 + wid * 64;

    const unsigned short* Qb = Q + (size_t)bh * Sn * HDn;
    const unsigned short* Kb = K + (size_t)bh * Sn * HDn;
    const unsigned short* Vb = Vt + (size_t)bh * HDn * Sn;

    int koff[2], voff[2];
    #pragma unroll
    for (int r = 0; r < 2; ++r) {
        int lin = (r * 256 + tid) * 16;
        int row = lin >> 7, colb = lin & 127;
        int scolb = colb ^ ((row & 7) << 4);
        koff[r] = row * HDn + (scolb >> 1);
        voff[r] = row * Sn + (scolb >> 1);
    }

    auto stage = [&](int buf, int key0) {
        #pragma unroll
        for (int r = 0; r < 2; ++r)
            __builtin_amdgcn_global_load_lds((gas1_t)(Kb + koff[r] + key0 * HDn),
                (gas3_t)(LDST + buf * 8192 + r * 2048 + wid * 512), 16, 0, 0);
        #pragma unroll
        for (int r = 0; r < 2; ++r)
            __builtin_amdgcn_global_load_lds((gas1_t)(Vb + voff[r] + key0),
                (gas3_t)(LDST + buf * 8192 + 4096 + r * 2048 + wid * 512), 16, 0, 0);
    };

    auto rdT = [&](int byteoff) -> bf16x8 {
        return *reinterpret_cast<const bf16x8*>((const char*)LDST + byteoff);
    };
    const int lrow = l31 * 128;
    const int lswz = (l31 & 7) << 4;

    bf16x8 qfA[4], qfB[4];
    #pragma unroll
    for (int sd = 0; sd < 4; ++sd) {
        qfA[sd] = *reinterpret_cast<const bf16x8*>(Qb + (size_t)(q0 + l31) * HDn + sd * 16 + h * 8);
        qfB[sd] = *reinterpret_cast<const bf16x8*>(Qb + (size_t)(q0 + 32 + l31) * HDn + sd * 16 + h * 8);
    }

    f32x16 oA0 = {}, oA1 = {}, oB0 = {}, oB1 = {};
    float lA = 0.f, lB = 0.f;

    stage(0, 0);
    __syncthreads();

    auto body = [&](int buf) {
        const int base = buf * 16384;
        bf16x8 ka0[4], ka1[4];
        #pragma unroll
        for (int sd = 0; sd < 4; ++sd) {
            int la = lrow + ((sd * 32 + h * 16) ^ lswz);
            ka0[sd] = rdT(base + la);
            ka1[sd] = rdT(base + 4096 + la);
        }
        f32x16 sA0 = {}, sA1 = {}, sB0 = {}, sB1 = {};
        __builtin_amdgcn_s_setprio(1);
        #pragma unroll
        for (int sd = 0; sd < 4; ++sd) sA0 = mfma32(ka0[sd], qfA[sd], sA0);
        #pragma unroll
        for (int sd = 0; sd < 4; ++sd) sA1 = mfma32(ka1[sd], qfA[sd], sA1);
        #pragma unroll
        for (int sd = 0; sd < 4; ++sd) sB0 = mfma32(ka0[sd], qfB[sd], sB0);
        #pragma unroll
        for (int sd = 0; sd < 4; ++sd) sB1 = mfma32(ka1[sd], qfB[sd], sB1);
        __builtin_amdgcn_s_setprio(0);

        bf16x8 va0[4], va1[4];
        #pragma unroll
        for (int S = 0; S < 4; ++S) {
            int la = lrow + ((S * 32 + h * 16) ^ lswz);
            va0[S] = rdT(base + 8192 + la);
            va1[S] = rdT(base + 8192 + 4096 + la);
        }

        #pragma unroll
        for (int r = 0; r < 16; ++r) {
            sA0[r] = exp2_raw(sA0[r]); sA1[r] = exp2_raw(sA1[r]);
            sB0[r] = exp2_raw(sB0[r]); sB1[r] = exp2_raw(sB1[r]);
        }

        {
            float sa[16], sb[16];
            #pragma unroll
            for (int r = 0; r < 16; ++r) { sa[r] = sA0[r] + sA1[r]; sb[r] = sB0[r] + sB1[r]; }
            #pragma unroll
            for (int st = 8; st > 0; st >>= 1)
                #pragma unroll
                for (int r = 0; r < 8; ++r)
                    if (r < st) { sa[r] += sa[r + st]; sb[r] += sb[r + st]; }
            lA += sa[0];
            lB += sb[0];
        }

        unsigned WpA[2][4][2], WpB[2][4][2];
        #pragma unroll
        for (int R = 0; R < 4; ++R) {
            WpA[0][R][0] = cvt_pk_bf16(sA0[4 * R],     sA0[4 * R + 1]);
            WpA[0][R][1] = cvt_pk_bf16(sA0[4 * R + 2], sA0[4 * R + 3]);
            WpA[1][R][0] = cvt_pk_bf16(sA1[4 * R],     sA1[4 * R + 1]);
            WpA[1][R][1] = cvt_pk_bf16(sA1[4 * R + 2], sA1[4 * R + 3]);
            WpB[0][R][0] = cvt_pk_bf16(sB0[4 * R],     sB0[4 * R + 1]);
            WpB[0][R][1] = cvt_pk_bf16(sB0[4 * R + 2], sB0[4 * R + 3]);
            WpB[1][R][0] = cvt_pk_bf16(sB1[4 * R],     sB1[4 * R + 1]);
            WpB[1][R][1] = cvt_pk_bf16(sB1[4 * R + 2], sB1[4 * R + 3]);
        }

        #pragma unroll
        for (int kc = 0; kc < 2; ++kc) {
            #pragma unroll
            for (int sp = 0; sp < 2; ++sp) {
                const int S = kc * 2 + sp;
                unsigned a0 = WpA[kc][2 * sp][0], a2 = WpA[kc][2 * sp + 1][0];
                unsigned a1 = WpA[kc][2 * sp][1], a3 = WpA[kc][2 * sp + 1][1];
                pl32swap(a0, a2);
                pl32swap(a1, a3);
                union { unsigned u[4]; bf16x8 v; } pbA;
                pbA.u[0] = a0; pbA.u[1] = a1; pbA.u[2] = a2; pbA.u[3] = a3;
                unsigned b0 = WpB[kc][2 * sp][0], b2 = WpB[kc][2 * sp + 1][0];
                unsigned b1 = WpB[kc][2 * sp][1], b3 = WpB[kc][2 * sp + 1][1];
                pl32swap(b0, b2);
                pl32swap(b1, b3);
                union { unsigned u[4]; bf16x8 v; } pbB;
                pbB.u[0] = b0; pbB.u[1] = b1; pbB.u[2] = b2; pbB.u[3] = b3;
                __builtin_amdgcn_s_setprio(1);
                oA0 = mfma32(va0[S], pbA.v, oA0);
                oA1 = mfma32(va1[S], pbA.v, oA1);
                oB0 = mfma32(va0[S], pbB.v, oB0);
                oB1 = mfma32(va1[S], pbB.v, oB1);
                __builtin_amdgcn_s_setprio(0);
            }
        }
    };

    constexpr int NT = Sn / 64;
    for (int kt = 0; kt < NT; kt += 2) {
        stage(1, (kt + 1) * 64);
        body(0);
        __syncthreads();
        if (kt + 2 < NT) stage(0, (kt + 2) * 64);
        body(1);
        __syncthreads();
    }

    lA += __shfl_xor(lA, 32, 64);
    lB += __shfl_xor(lB, 32, 64);
    const float invA = 1.f / lA, invB = 1.f / lB;
    const int b = bh >> 4, hh = bh & 15;
    unsigned short* OrowA = On + ((size_t)b * Sn + (q0 + l31))      * Hn + hh * 64;
    unsigned short* OrowB = On + ((size_t)b * Sn + (q0 + 32 + l31)) * Hn + hh * 64;
    #pragma unroll
    for (int g = 0; g < 4; ++g) {
        union { unsigned u[2]; bf16x4 s; } pA0, pA1, pB0, pB1;
        pA0.u[0] = cvt_pk_bf16(oA0[4 * g] * invA,     oA0[4 * g + 1] * invA);
        pA0.u[1] = cvt_pk_bf16(oA0[4 * g + 2] * invA, oA0[4 * g + 3] * invA);
        pA1.u[0] = cvt_pk_bf16(oA1[4 * g] * invA,     oA1[4 * g + 1] * invA);
        pA1.u[1] = cvt_pk_bf16(oA1[4 * g + 2] * invA, oA1[4 * g + 3] * invA);
        pB0.u[0] = cvt_pk_bf16(oB0[4 * g] * invB,     oB0[4 * g + 1] * invB);
        pB0.u[1] = cvt_pk_bf16(oB0[4 * g + 2] * invB, oB0[4 * g + 3] * invB);
        pB1.u[0] = cvt_pk_bf16(oB1[4 * g] * invB,     oB1[4 * g + 1] * invB);
        pB1.u[1] = cvt_pk_bf16(oB1[4 * g + 2] * invB, oB1[4 * g + 3] * invB);
        *reinterpret_cast<bf16x4*>(OrowA + g * 8 + 4 * h)      = pA0.s;
        *reinterpret_cast<bf16x4*>(OrowA + 32 + g * 8 + 4 * h) = pA1.s;
        *reinterpret_cast<bf16x4*>(OrowB + g * 8 + 4 * h)      = pB0.s;
        *reinterpret_cast<bf16x4*>(OrowB + 32 + g * 8 + 4 * h) = pB1.s;
    }
}

// ---------------- launch ----------------
extern "C" void kernel_launch(void* const* d_in, const int* in_sizes, int n_in,
                              void* d_out, int out_size, void* d_ws, size_t ws_size,
                              hipStream_t stream)
{
    (void)in_sizes; (void)n_in; (void)out_size;
    const float* q  = (const float*)d_in[0];
    const float* k  = (const float*)d_in[1];
    const float* v  = (const float*)d_in[2];
    const float* Wq = (const float*)d_in[3];
    const float* bq = (const float*)d_in[4];
    const float* Wk = (const float*)d_in[5];
    const float* bk = (const float*)d_in[6];
    const float* Wv = (const float*)d_in[7];
    const float* bv = (const float*)d_in[8];
    const float* Wo = (const float*)d_in[9];
    const float* bo = (const float*)d_in[10];
    float* out = (float*)d_out;

    if (ws_size < (size_t)72 * 1024 * 1024) return;

    unsigned short* Wb = (unsigned short*)d_ws;
    unsigned short* Qw = Wb + (size_t)4 * 1024 * 1024;
    unsigned short* Kw = Qw + (size_t)8 * 1024 * 1024;
    unsigned short* Vw = Kw + (size_t)8 * 1024 * 1024;
    unsigned short* Aw = Vw + (size_t)8 * 1024 * 1024;

    convert_w_kernel<<<4096, 256, 0, stream>>>(Wq, Wk, Wv, Wo, Wb);
    qkv_proj_kernel<<<dim3(512, 1, 3), 256, 0, stream>>>(q, k, v, Wb, bq, bk, bv, Qw, Kw, Vw);
    attn_kernel<<<512, 256, 0, stream>>>(Qw, Kw, Vw, Aw);
    out_proj_kernel<<<512, 256, 0, stream>>>(Aw, Wb + ((size_t)3 << 20), bo, out);
}